// Round 1
// baseline (237.432 us; speedup 1.0000x reference)
//
#include <hip/hip_runtime.h>

// EfficientAttention (linear attention / Performer-style), MI355X gfx950.
// B=4, S=8192, H=512, NH=8, HD=64, FD=32. All inputs fp32; output fp32.
//
// Pipeline (all bf16-MFMA internally, fp32 accumulate):
//  K0a cvt_x   : x fp32 -> xb bf16                        (32768 x 512)
//  K0b prep_w  : WcatT[n][k] bf16, n<256: (Wq@rm)^T, n<512: (Wk@rm)^T, else Wv^T
//                WoutT[n][k] bf16 = W_out[k][n]
//  K1  gemm<0> : xb @ WcatT^T; epilogue: elu+1 on feature cols;
//                QF token-major (32768x256), KFT/VT transposed (bh,d|f,s)
//  K2  kv_part : per (b,h): kv[d][f] = sum_s k'[s][d] v[s][f] via MFMA (K=s),
//                ksum folded via shuffle-reduce of A-frags; split-S partials
//  K2b kv_red  : reduce partials -> kvr[bh][2080] (2048 kv + 32 ksum) fp32
//  K3  z_kernel: num = q'@kv, den = q'@ksum (5th B-frag col); z bf16
//  K4  gemm<1> : z @ WoutT^T + b_out -> out fp32

#define DEVFN static __device__ __forceinline__

typedef short short8 __attribute__((ext_vector_type(8)));
typedef __bf16 bf16x8 __attribute__((ext_vector_type(8)));
typedef float f32x4 __attribute__((ext_vector_type(4)));

DEVFN unsigned short f2bf(float x) {
  unsigned u = __float_as_uint(x);
  u += 0x7FFFu + ((u >> 16) & 1u);   // RNE
  return (unsigned short)(u >> 16);
}
DEVFN float bf2f(unsigned short s) { return __uint_as_float(((unsigned)s) << 16); }

DEVFN f32x4 mfma16(short8 a, short8 b, f32x4 c) {
  return __builtin_amdgcn_mfma_f32_16x16x32_bf16(
      __builtin_bit_cast(bf16x8, a), __builtin_bit_cast(bf16x8, b), c, 0, 0, 0);
}

DEVFN void gload16(const void* g, void* l) {
  __builtin_amdgcn_global_load_lds((__attribute__((address_space(1))) unsigned*)g,
                                   (__attribute__((address_space(3))) unsigned*)l,
                                   16, 0, 0);
}

// ---------------- K0a: x fp32 -> bf16 ----------------
__global__ __launch_bounds__(256) void cvt_x(const float* __restrict__ x,
                                             unsigned short* __restrict__ xb) {
  size_t i = ((size_t)blockIdx.x * 256 + threadIdx.x) * 8;
  f32x4 a = *(const f32x4*)(x + i);
  f32x4 b = *(const f32x4*)(x + i + 4);
  short8 o;
  o[0] = (short)f2bf(a[0]); o[1] = (short)f2bf(a[1]);
  o[2] = (short)f2bf(a[2]); o[3] = (short)f2bf(a[3]);
  o[4] = (short)f2bf(b[0]); o[5] = (short)f2bf(b[1]);
  o[6] = (short)f2bf(b[2]); o[7] = (short)f2bf(b[3]);
  *(short8*)(xb + i) = o;
}

// ---------------- K0b: weight prep ----------------
// blocks 0..255: q-feature rows, 256..511: k-feature rows, 512..1023: v rows,
// 1024..1535: WoutT rows.
__global__ __launch_bounds__(64) void prep_w(const float* __restrict__ Wqkv,
                                             const float* __restrict__ rm,
                                             const float* __restrict__ Wout,
                                             unsigned short* __restrict__ WcatT,
                                             unsigned short* __restrict__ WoutT) {
  const int n = blockIdx.x, t = threadIdx.x;
  if (n < 512) {
    const int isK = (n >= 256) ? 1 : 0;
    const int c = n & 255, h = c >> 5, d = c & 31;
    const int colbase = isK * 512 + h * 64;
    for (int k = t; k < 512; k += 64) {
      float s = 0.f;
      const float* wrow = Wqkv + (size_t)k * 1536 + colbase;
      #pragma unroll 8
      for (int e = 0; e < 64; ++e) s += wrow[e] * rm[e * 32 + d];
      WcatT[(size_t)n * 512 + k] = f2bf(s);
    }
  } else if (n < 1024) {
    const int c = n - 512;
    for (int k = t; k < 512; k += 64)
      WcatT[(size_t)n * 512 + k] = f2bf(Wqkv[(size_t)k * 1536 + 1024 + c]);
  } else {
    const int c = n - 1024;
    for (int k = t; k < 512; k += 64)
      WoutT[(size_t)c * 512 + k] = f2bf(Wout[(size_t)k * 512 + c]);
  }
}

// ---------------- K1 / K4: 128x128-tile bf16 GEMM, B^T input ----------------
// MODE 0: epilogue elu+1 on cols<512, scatter to QF / KFT / VT (bf16)
// MODE 1: fp32 out + bias, N=512
template <int MODE>
__global__ __launch_bounds__(256) void gemm_bt(
    const unsigned short* __restrict__ A,   // M x K bf16, row-major
    const unsigned short* __restrict__ BT,  // N x K bf16, row-major (B transposed)
    unsigned short* __restrict__ OQ,        // MODE0
    unsigned short* __restrict__ OK,        // MODE0 (transposed layout)
    unsigned short* __restrict__ OV,        // MODE0 (transposed layout)
    float* __restrict__ OC,                 // MODE1
    const float* __restrict__ bias,         // MODE1
    int K) {
  __shared__ __attribute__((aligned(16))) unsigned short As[128 * 32];
  __shared__ __attribute__((aligned(16))) unsigned short Bs[128 * 32];
  const int t = threadIdx.x;
  const int lane = t & 63, w = t >> 6;
  const int wr = w >> 1, wc = w & 1;
  const int col = lane & 15, kg = lane >> 4;
  const long m0 = (long)blockIdx.y * 128;
  const long n0 = (long)blockIdx.x * 128;

  const unsigned short* ga = A + (m0 + (t >> 2)) * K + (t & 3) * 8;
  const unsigned short* gb = BT + (n0 + (t >> 2)) * K + (t & 3) * 8;
  unsigned short* lA0 = As + w * 512;   // wave-uniform LDS base, lane adds i*16B
  unsigned short* lB0 = Bs + w * 512;

  f32x4 acc[4][4] = {};

  const int nk = K >> 5;
  for (int kt = 0; kt < nk; ++kt) {
    __syncthreads();                       // prev tile's reads done
    const int ko = kt * 32;
    gload16(ga + ko, lA0);
    gload16(ga + 64 * K + ko, lA0 + 2048);
    gload16(gb + ko, lB0);
    gload16(gb + 64 * K + ko, lB0 + 2048);
    __syncthreads();                       // drains vmcnt(0) before barrier
    short8 af[4], bfr[4];
    #pragma unroll
    for (int mi = 0; mi < 4; ++mi)
      af[mi] = *(const short8*)&As[(wr * 64 + mi * 16 + col) * 32 + kg * 8];
    #pragma unroll
    for (int ni = 0; ni < 4; ++ni)
      bfr[ni] = *(const short8*)&Bs[(wc * 64 + ni * 16 + col) * 32 + kg * 8];
    #pragma unroll
    for (int mi = 0; mi < 4; ++mi)
      #pragma unroll
      for (int ni = 0; ni < 4; ++ni)
        acc[mi][ni] = mfma16(af[mi], bfr[ni], acc[mi][ni]);
  }

  const int rowb = (int)m0 + wr * 64;
  const int colb = (int)n0 + wc * 64;
  if (MODE == 0) {
    #pragma unroll
    for (int ni = 0; ni < 4; ++ni) {
      const int c = colb + ni * 16 + col;
      #pragma unroll
      for (int mi = 0; mi < 4; ++mi) {
        #pragma unroll
        for (int r = 0; r < 4; ++r) {
          const int row = rowb + mi * 16 + kg * 4 + r;  // token
          float v = acc[mi][ni][r];
          const int b = row >> 13, s = row & 8191;
          if (c < 512) {
            v = v > 0.f ? v + 1.f : __expf(v);          // elu(v)+1
            if (c < 256) {
              OQ[(size_t)row * 256 + c] = f2bf(v);
            } else {
              const int cc = c - 256, h = cc >> 5, d = cc & 31;
              OK[((size_t)(b * 8 + h) * 32 + d) * 8192 + s] = f2bf(v);
            }
          } else {
            const int cc = c - 512, h = cc >> 6, f = cc & 63;
            OV[((size_t)(b * 8 + h) * 64 + f) * 8192 + s] = f2bf(v);
          }
        }
      }
    }
  } else {
    #pragma unroll
    for (int ni = 0; ni < 4; ++ni) {
      const int c = colb + ni * 16 + col;
      const float bb = bias[c];
      #pragma unroll
      for (int mi = 0; mi < 4; ++mi) {
        #pragma unroll
        for (int r = 0; r < 4; ++r) {
          const int row = rowb + mi * 16 + kg * 4 + r;
          OC[(size_t)row * 512 + c] = acc[mi][ni][r] + bb;
        }
      }
    }
  }
}

// ---------------- K2: kv partials per (b,h), split over S ----------------
// 1 wave/block. A = k'^T (32 x S) from KFT, B = v (S x 64) from VT;
// both read as direct 16B global loads in MFMA fragment order.
__global__ __launch_bounds__(64) void kv_partial(const unsigned short* __restrict__ KFT,
                                                 const unsigned short* __restrict__ VT,
                                                 float* __restrict__ part) {
  const int bh = blockIdx.x, chunk = blockIdx.y;
  const int l = threadIdx.x;
  const int col = l & 15, kg = l >> 4;
  const unsigned short* Ab = KFT + (size_t)bh * 32 * 8192;
  const unsigned short* Bb = VT + (size_t)bh * 64 * 8192;
  const int s0 = chunk * 256;
  f32x4 acc[2][4] = {};
  float ksp[2] = {0.f, 0.f};
  for (int st = 0; st < 8; ++st) {
    const int s = s0 + st * 32 + kg * 8;
    short8 a[2], b[4];
    #pragma unroll
    for (int mi = 0; mi < 2; ++mi)
      a[mi] = *(const short8*)&Ab[(size_t)(mi * 16 + col) * 8192 + s];
    #pragma unroll
    for (int ni = 0; ni < 4; ++ni)
      b[ni] = *(const short8*)&Bb[(size_t)(ni * 16 + col) * 8192 + s];
    #pragma unroll
    for (int mi = 0; mi < 2; ++mi) {
      #pragma unroll
      for (int j = 0; j < 8; ++j) ksp[mi] += bf2f((unsigned short)a[mi][j]);
      #pragma unroll
      for (int ni = 0; ni < 4; ++ni)
        acc[mi][ni] = mfma16(a[mi], b[ni], acc[mi][ni]);
    }
  }
  #pragma unroll
  for (int mi = 0; mi < 2; ++mi) {   // reduce ksum over the 4 k-groups
    float v = ksp[mi];
    v += __shfl_xor(v, 16);
    v += __shfl_xor(v, 32);
    ksp[mi] = v;
  }
  float* p = part + ((size_t)bh * 32 + chunk) * 2080;
  #pragma unroll
  for (int mi = 0; mi < 2; ++mi)
    #pragma unroll
    for (int ni = 0; ni < 4; ++ni)
      #pragma unroll
      for (int r = 0; r < 4; ++r) {
        const int d = mi * 16 + kg * 4 + r, f = ni * 16 + col;
        p[d * 64 + f] = acc[mi][ni][r];
      }
  if (kg == 0) {
    p[2048 + col] = ksp[0];
    p[2048 + 16 + col] = ksp[1];
  }
}

// ---------------- K2b: reduce partials ----------------
__global__ __launch_bounds__(256) void kv_reduce(const float* __restrict__ part,
                                                 float* __restrict__ kvr) {
  const int bh = blockIdx.x, t = threadIdx.x;
  for (int idx = t; idx < 2080; idx += 256) {
    float s = 0.f;
    for (int c = 0; c < 32; ++c) s += part[((size_t)bh * 32 + c) * 2080 + idx];
    kvr[(size_t)bh * 2080 + idx] = s;
  }
}

// ---------------- K3: z = (q' @ kv) / (q' @ ksum + 1e-6) ----------------
__global__ __launch_bounds__(256) void z_kernel(const unsigned short* __restrict__ QF,
                                                const float* __restrict__ kvr,
                                                unsigned short* __restrict__ Z) {
  const int bh = blockIdx.x, b = bh >> 3, h = bh & 7;
  const int chunk = blockIdx.y;
  const int t = threadIdx.x, l = t & 63, w = t >> 6;
  const int col = l & 15, kg = l >> 4;
  const float* kvp = kvr + (size_t)bh * 2080;
  short8 bfr[5];
  #pragma unroll
  for (int ni = 0; ni < 4; ++ni)
    #pragma unroll
    for (int j = 0; j < 8; ++j)
      bfr[ni][j] = (short)f2bf(kvp[(kg * 8 + j) * 64 + ni * 16 + col]);
  #pragma unroll
  for (int j = 0; j < 8; ++j)
    bfr[4][j] = (col == 0) ? (short)f2bf(kvp[2048 + kg * 8 + j]) : (short)0;

  const int sbase = chunk * 256 + w * 64;
  for (int g = 0; g < 4; ++g) {
    const int s0 = sbase + g * 16;
    const size_t tok0 = (size_t)b * 8192 + s0;
    short8 av = *(const short8*)&QF[(tok0 + col) * 256 + h * 32 + kg * 8];
    f32x4 zero = {};
    f32x4 acc[5];
    #pragma unroll
    for (int n = 0; n < 5; ++n) acc[n] = mfma16(av, bfr[n], zero);
    #pragma unroll
    for (int r = 0; r < 4; ++r) {
      const float den = __shfl(acc[4][r], (l & 48));
      const float inv = 1.f / (den + 1e-6f);
      #pragma unroll
      for (int n = 0; n < 4; ++n) {
        const float zv = acc[n][r] * inv;
        Z[(tok0 + kg * 4 + r) * 512 + h * 64 + n * 16 + col] = f2bf(zv);
      }
    }
  }
}

extern "C" void kernel_launch(void* const* d_in, const int* in_sizes, int n_in,
                              void* d_out, int out_size, void* d_ws, size_t ws_size,
                              hipStream_t stream) {
  const float* x    = (const float*)d_in[0];  // (4,8192,512)
  const float* Wqkv = (const float*)d_in[1];  // (512,1536)
  const float* rm   = (const float*)d_in[2];  // (64,32)
  const float* Wout = (const float*)d_in[3];  // (512,512)
  const float* bout = (const float*)d_in[4];  // (512,)
  float* out = (float*)d_out;                 // (4,8192,512) fp32

  char* ws = (char*)d_ws;
  unsigned short* xb    = (unsigned short*)(ws);              // 33,554,432 B
  unsigned short* WcatT = (unsigned short*)(ws + 33554432);   //  1,048,576
  unsigned short* WoutT = (unsigned short*)(ws + 34603008);   //    524,288
  unsigned short* QF    = (unsigned short*)(ws + 35127296);   // 16,777,216
  unsigned short* KFT   = (unsigned short*)(ws + 51904512);   // 16,777,216
  unsigned short* VT    = (unsigned short*)(ws + 68681728);   // 33,554,432
  float* part           = (float*)(ws + 102236160);           //  8,519,680
  float* kvr            = (float*)(ws + 110755840);           //    266,240
  unsigned short* Z = xb;  // alias: xb dead after gemm<0>

  if (ws_size < 111022080u) return;  // insufficient workspace: fail loudly

  cvt_x<<<dim3(8192), dim3(256), 0, stream>>>(x, xb);
  prep_w<<<dim3(1536), dim3(64), 0, stream>>>(Wqkv, rm, Wout, WcatT, WoutT);
  gemm_bt<0><<<dim3(8, 256), dim3(256), 0, stream>>>(xb, WcatT, QF, KFT, VT,
                                                     nullptr, nullptr, 512);
  kv_partial<<<dim3(32, 32), dim3(64), 0, stream>>>(KFT, VT, part);
  kv_reduce<<<dim3(32), dim3(256), 0, stream>>>(part, kvr);
  z_kernel<<<dim3(32, 32), dim3(256), 0, stream>>>(QF, kvr, Z);
  gemm_bt<1><<<dim3(4, 256), dim3(256), 0, stream>>>(Z, WoutT, nullptr, nullptr,
                                                     nullptr, out, bout, 512);
}

// Round 2
// 225.844 us; speedup vs baseline: 1.0513x; 1.0513x over previous
//
#include <hip/hip_runtime.h>

// EfficientAttention (linear attention / Performer-style), MI355X gfx950.
// B=4, S=8192, H=512, NH=8, HD=64, FD=32. All inputs fp32; output fp32.
//
// R2 pipeline (bf16 MFMA, fp32 accumulate), with output-projection fusion:
//  K0a cvt_x   : x fp32 -> xb bf16
//  K0b prep_w  : WcatT[n][k] bf16 (n<256: (Wq@rm)^T, n<512: (Wk@rm)^T, else Wv^T)
//  K1  gemm<0> : xb @ WcatT^T; elu+1 on feature cols; QF token-major,
//                KFT/VT transposed (bh,d|f,s).  2-phase dbuf + XCD swizzle.
//  K2  kv_part : per (b,h): kv[d][f] = sum_s k'[s][d] v[s][f]; ksum folded.
//  K2b kv_red  : partials -> kvr[bh][2080] (2048 kv + 32 ksum) fp32
//  K2c mprep   : MT[b][n][k=h*32+d] = sum_f kv[b,h,d,f] * Wout[h*64+f][n]  (bf16)
//  K3  qn_kern : qn[tok][h*32+d] = q' / (q'.ksum_h + 1e-6)                  (bf16)
//  K4  gemm<1> : out[b] = qn[b] @ M[b] + b_out   (K=256, per-batch B)

#define DEVFN static __device__ __forceinline__

typedef short short8 __attribute__((ext_vector_type(8)));
typedef __bf16 bf16x8 __attribute__((ext_vector_type(8)));
typedef float f32x4 __attribute__((ext_vector_type(4)));

DEVFN unsigned short f2bf(float x) {
  unsigned u = __float_as_uint(x);
  u += 0x7FFFu + ((u >> 16) & 1u);   // RNE
  return (unsigned short)(u >> 16);
}
DEVFN float bf2f(unsigned short s) { return __uint_as_float(((unsigned)s) << 16); }

DEVFN f32x4 mfma16(short8 a, short8 b, f32x4 c) {
  return __builtin_amdgcn_mfma_f32_16x16x32_bf16(
      __builtin_bit_cast(bf16x8, a), __builtin_bit_cast(bf16x8, b), c, 0, 0, 0);
}

DEVFN void gload16(const void* g, void* l) {
  __builtin_amdgcn_global_load_lds((__attribute__((address_space(1))) unsigned*)g,
                                   (__attribute__((address_space(3))) unsigned*)l,
                                   16, 0, 0);
}

// ---------------- K0a: x fp32 -> bf16 ----------------
__global__ __launch_bounds__(256) void cvt_x(const float* __restrict__ x,
                                             unsigned short* __restrict__ xb) {
  size_t i = ((size_t)blockIdx.x * 256 + threadIdx.x) * 8;
  f32x4 a = *(const f32x4*)(x + i);
  f32x4 b = *(const f32x4*)(x + i + 4);
  short8 o;
  o[0] = (short)f2bf(a[0]); o[1] = (short)f2bf(a[1]);
  o[2] = (short)f2bf(a[2]); o[3] = (short)f2bf(a[3]);
  o[4] = (short)f2bf(b[0]); o[5] = (short)f2bf(b[1]);
  o[6] = (short)f2bf(b[2]); o[7] = (short)f2bf(b[3]);
  *(short8*)(xb + i) = o;
}

// ---------------- K0b: weight prep (WcatT only) ----------------
__global__ __launch_bounds__(64) void prep_w(const float* __restrict__ Wqkv,
                                             const float* __restrict__ rm,
                                             unsigned short* __restrict__ WcatT) {
  const int n = blockIdx.x, t = threadIdx.x;
  if (n < 512) {
    const int isK = (n >= 256) ? 1 : 0;
    const int c = n & 255, h = c >> 5, d = c & 31;
    const int colbase = isK * 512 + h * 64;
    for (int k = t; k < 512; k += 64) {
      float s = 0.f;
      const float* wrow = Wqkv + (size_t)k * 1536 + colbase;
      #pragma unroll 8
      for (int e = 0; e < 64; ++e) s += wrow[e] * rm[e * 32 + d];
      WcatT[(size_t)n * 512 + k] = f2bf(s);
    }
  } else {
    const int c = n - 512;
    for (int k = t; k < 512; k += 64)
      WcatT[(size_t)n * 512 + k] = f2bf(Wqkv[(size_t)k * 1536 + 1024 + c]);
  }
}

// ---------------- K1 / K4: 128x128-tile bf16 GEMM, 2-phase dbuf ----------------
// MODE 0: epilogue elu+1 on cols<512, scatter to QF / KFT / VT (bf16)
// MODE 1: fp32 out + bias, per-batch BT (bstride elements per batch of 8192 rows)
template <int MODE>
__global__ __launch_bounds__(256) void gemm_bt(
    const unsigned short* __restrict__ A,   // M x K bf16, row-major
    const unsigned short* __restrict__ BT,  // N x K bf16, row-major (B^T)
    unsigned short* __restrict__ OQ,        // MODE0
    unsigned short* __restrict__ OK,        // MODE0 (bh,d,s)
    unsigned short* __restrict__ OV,        // MODE0 (bh,f,s)
    float* __restrict__ OC,                 // MODE1
    const float* __restrict__ bias,         // MODE1
    int K, long bstride) {
  __shared__ __attribute__((aligned(16))) unsigned short As[2][128 * 32];
  __shared__ __attribute__((aligned(16))) unsigned short Bs[2][128 * 32];
  const int t = threadIdx.x;
  const int lane = t & 63, w = t >> 6;
  const int wr = w >> 1, wc = w & 1;
  const int col = lane & 15, kg = lane >> 4;

  // XCD-chunked swizzle (nwg divisible by 8): each XCD takes a contiguous
  // m-range so A-panels stay resident in its private L2.
  const int nx = gridDim.x;
  int wg = blockIdx.y * nx + blockIdx.x;
  const int cpx = (nx * gridDim.y) >> 3;
  wg = (wg & 7) * cpx + (wg >> 3);
  const int bx = wg % nx, by = wg / nx;

  const long m0 = (long)by * 128;
  const long n0 = (long)bx * 128;
  const long b = m0 >> 13;  // batch (8192 tokens each); tiles never straddle

  const unsigned short* ga = A + (m0 + (t >> 2)) * K + (t & 3) * 8;
  const unsigned short* gb = BT + ((MODE == 1) ? b * bstride : 0) +
                             (n0 + (t >> 2)) * K + (t & 3) * 8;
  f32x4 acc[4][4] = {};

  const int nk = K >> 5;
#define STAGE(buf, kt)                                    \
  {                                                       \
    const int ko = (kt) * 32;                             \
    gload16(ga + ko, As[buf] + w * 512);                  \
    gload16(ga + 64 * K + ko, As[buf] + w * 512 + 2048);  \
    gload16(gb + ko, Bs[buf] + w * 512);                  \
    gload16(gb + 64 * K + ko, Bs[buf] + w * 512 + 2048);  \
  }
  STAGE(0, 0);
  __syncthreads();   // implicit vmcnt(0) drain: tile 0 resident
  int buf = 0;
  for (int kt = 0; kt < nk; ++kt) {
    if (kt + 1 < nk) STAGE(buf ^ 1, kt + 1);  // issue next tile EARLY
    short8 af[4], bfr[4];
    #pragma unroll
    for (int mi = 0; mi < 4; ++mi)
      af[mi] = *(const short8*)&As[buf][(wr * 64 + mi * 16 + col) * 32 + kg * 8];
    #pragma unroll
    for (int ni = 0; ni < 4; ++ni)
      bfr[ni] = *(const short8*)&Bs[buf][(wc * 64 + ni * 16 + col) * 32 + kg * 8];
    #pragma unroll
    for (int mi = 0; mi < 4; ++mi)
      #pragma unroll
      for (int ni = 0; ni < 4; ++ni)
        acc[mi][ni] = mfma16(af[mi], bfr[ni], acc[mi][ni]);
    __syncthreads();  // drains next-tile loads; all waves done reading buf
    buf ^= 1;
  }
#undef STAGE

  const int rowb = (int)m0 + wr * 64;
  const int colb = (int)n0 + wc * 64;
  if (MODE == 0) {
    #pragma unroll
    for (int ni = 0; ni < 4; ++ni) {
      const int c = colb + ni * 16 + col;
      #pragma unroll
      for (int mi = 0; mi < 4; ++mi) {
        #pragma unroll
        for (int r = 0; r < 4; ++r) {
          const int row = rowb + mi * 16 + kg * 4 + r;  // token
          float v = acc[mi][ni][r];
          const int bb = row >> 13, s = row & 8191;
          if (c < 512) {
            v = v > 0.f ? v + 1.f : __expf(v);          // elu(v)+1
            if (c < 256) {
              OQ[(size_t)row * 256 + c] = f2bf(v);
            } else {
              const int cc = c - 256, h = cc >> 5, d = cc & 31;
              OK[((size_t)(bb * 8 + h) * 32 + d) * 8192 + s] = f2bf(v);
            }
          } else {
            const int cc = c - 512, h = cc >> 6, f = cc & 63;
            OV[((size_t)(bb * 8 + h) * 64 + f) * 8192 + s] = f2bf(v);
          }
        }
      }
    }
  } else {
    #pragma unroll
    for (int ni = 0; ni < 4; ++ni) {
      const int c = colb + ni * 16 + col;
      const float bb = bias[c];
      #pragma unroll
      for (int mi = 0; mi < 4; ++mi) {
        #pragma unroll
        for (int r = 0; r < 4; ++r) {
          const int row = rowb + mi * 16 + kg * 4 + r;
          OC[(size_t)row * 512 + c] = acc[mi][ni][r] + bb;
        }
      }
    }
  }
}

// ---------------- K2: kv partials per (b,h), split over S ----------------
__global__ __launch_bounds__(64) void kv_partial(const unsigned short* __restrict__ KFT,
                                                 const unsigned short* __restrict__ VT,
                                                 float* __restrict__ part) {
  const int bh = blockIdx.x, chunk = blockIdx.y;
  const int l = threadIdx.x;
  const int col = l & 15, kg = l >> 4;
  const unsigned short* Ab = KFT + (size_t)bh * 32 * 8192;
  const unsigned short* Bb = VT + (size_t)bh * 64 * 8192;
  const int s0 = chunk * 256;
  f32x4 acc[2][4] = {};
  float ksp[2] = {0.f, 0.f};
  for (int st = 0; st < 8; ++st) {
    const int s = s0 + st * 32 + kg * 8;
    short8 a[2], b[4];
    #pragma unroll
    for (int mi = 0; mi < 2; ++mi)
      a[mi] = *(const short8*)&Ab[(size_t)(mi * 16 + col) * 8192 + s];
    #pragma unroll
    for (int ni = 0; ni < 4; ++ni)
      b[ni] = *(const short8*)&Bb[(size_t)(ni * 16 + col) * 8192 + s];
    #pragma unroll
    for (int mi = 0; mi < 2; ++mi) {
      #pragma unroll
      for (int j = 0; j < 8; ++j) ksp[mi] += bf2f((unsigned short)a[mi][j]);
      #pragma unroll
      for (int ni = 0; ni < 4; ++ni)
        acc[mi][ni] = mfma16(a[mi], b[ni], acc[mi][ni]);
    }
  }
  #pragma unroll
  for (int mi = 0; mi < 2; ++mi) {
    float v = ksp[mi];
    v += __shfl_xor(v, 16);
    v += __shfl_xor(v, 32);
    ksp[mi] = v;
  }
  float* p = part + ((size_t)bh * 32 + chunk) * 2080;
  #pragma unroll
  for (int mi = 0; mi < 2; ++mi)
    #pragma unroll
    for (int ni = 0; ni < 4; ++ni)
      #pragma unroll
      for (int r = 0; r < 4; ++r) {
        const int d = mi * 16 + kg * 4 + r, f = ni * 16 + col;
        p[d * 64 + f] = acc[mi][ni][r];
      }
  if (kg == 0) {
    p[2048 + col] = ksp[0];
    p[2048 + 16 + col] = ksp[1];
  }
}

// ---------------- K2b: reduce partials ----------------
__global__ __launch_bounds__(256) void kv_reduce(const float* __restrict__ part,
                                                 float* __restrict__ kvr) {
  const int bh = blockIdx.x, t = threadIdx.x;
  for (int idx = t; idx < 2080; idx += 256) {
    float s = 0.f;
    for (int c = 0; c < 32; ++c) s += part[((size_t)bh * 32 + c) * 2080 + idx];
    kvr[(size_t)bh * 2080 + idx] = s;
  }
}

// ---------------- K2c: MT[b][n][k=h*32+d] = sum_f kv[b,h,d,f]*Wout[h*64+f][n] ----
__global__ __launch_bounds__(256) void mprep(const float* __restrict__ kvr,
                                             const float* __restrict__ Wout,
                                             unsigned short* __restrict__ MT) {
  const int bx = blockIdx.x;            // 0..2047
  const int b = bx >> 9, n = bx & 511;
  const int k = threadIdx.x;            // 0..255
  const int h = k >> 5, d = k & 31;
  const float* kvp = kvr + (size_t)(b * 8 + h) * 2080 + d * 64;
  const float* wp = Wout + (size_t)h * 64 * 512 + n;
  float s = 0.f;
  #pragma unroll 8
  for (int f = 0; f < 64; ++f) s += kvp[f] * wp[(size_t)f * 512];
  MT[((size_t)b * 512 + n) * 256 + k] = f2bf(s);
}

// ---------------- K3: qn = q' / (q'.ksum + 1e-6) ----------------
__global__ __launch_bounds__(256) void qn_kernel(const unsigned short* __restrict__ QF,
                                                 const float* __restrict__ kvr,
                                                 unsigned short* __restrict__ QN) {
  __shared__ float ks[256];             // 8 heads x 32 for this batch
  const int t = threadIdx.x;
  const size_t tid = (size_t)blockIdx.x * 256 + t;
  const int tok0 = blockIdx.x * 32;     // 32 tokens per block, same batch
  const int b = tok0 >> 13;
  ks[t] = kvr[(size_t)(b * 8 + (t >> 5)) * 2080 + 2048 + (t & 31)];
  __syncthreads();
  const int tok = (int)(tid >> 3), h = (int)(tid & 7);
  const short8* q = (const short8*)(QF + (size_t)tok * 256 + h * 32);
  short8 v[4];
  #pragma unroll
  for (int i = 0; i < 4; ++i) v[i] = q[i];
  float den = 1e-6f;
  #pragma unroll
  for (int i = 0; i < 4; ++i)
    #pragma unroll
    for (int j = 0; j < 8; ++j)
      den += bf2f((unsigned short)v[i][j]) * ks[h * 32 + i * 8 + j];
  const float inv = 1.f / den;
  short8* o = (short8*)(QN + (size_t)tok * 256 + h * 32);
  #pragma unroll
  for (int i = 0; i < 4; ++i) {
    short8 ov;
    #pragma unroll
    for (int j = 0; j < 8; ++j)
      ov[j] = (short)f2bf(bf2f((unsigned short)v[i][j]) * inv);
    o[i] = ov;
  }
}

extern "C" void kernel_launch(void* const* d_in, const int* in_sizes, int n_in,
                              void* d_out, int out_size, void* d_ws, size_t ws_size,
                              hipStream_t stream) {
  const float* x    = (const float*)d_in[0];  // (4,8192,512)
  const float* Wqkv = (const float*)d_in[1];  // (512,1536)
  const float* rm   = (const float*)d_in[2];  // (64,32)
  const float* Wout = (const float*)d_in[3];  // (512,512)
  const float* bout = (const float*)d_in[4];  // (512,)
  float* out = (float*)d_out;                 // (4,8192,512) fp32

  char* ws = (char*)d_ws;
  unsigned short* xb    = (unsigned short*)(ws);              // 33,554,432 B
  unsigned short* WcatT = (unsigned short*)(ws + 33554432);   //  1,048,576
  unsigned short* QF    = (unsigned short*)(ws + 35127296);   // 16,777,216
  unsigned short* KFT   = (unsigned short*)(ws + 51904512);   // 16,777,216
  unsigned short* VT    = (unsigned short*)(ws + 68681728);   // 33,554,432
  float* part           = (float*)(ws + 102236160);           //  8,519,680
  float* kvr            = (float*)(ws + 110755840);           //    266,240
  unsigned short* QN = xb;                                    // alias, xb dead
  unsigned short* MT = (unsigned short*)(ws + 16777216);      // alias, 1 MB

  if (ws_size < 111022080u) return;

  cvt_x<<<dim3(8192), dim3(256), 0, stream>>>(x, xb);
  prep_w<<<dim3(1024), dim3(64), 0, stream>>>(Wqkv, rm, WcatT);
  gemm_bt<0><<<dim3(8, 256), dim3(256), 0, stream>>>(xb, WcatT, QF, KFT, VT,
                                                     nullptr, nullptr, 512, 0);
  kv_partial<<<dim3(32, 32), dim3(64), 0, stream>>>(KFT, VT, part);
  kv_reduce<<<dim3(32), dim3(256), 0, stream>>>(part, kvr);
  mprep<<<dim3(2048), dim3(256), 0, stream>>>(kvr, Wout, MT);
  qn_kernel<<<dim3(1024), dim3(256), 0, stream>>>(QF, kvr, QN);
  gemm_bt<1><<<dim3(4, 256), dim3(256), 0, stream>>>(QN, MT, nullptr, nullptr,
                                                     nullptr, out, bout, 256,
                                                     512 * 256);
}

// Round 5
// 183.304 us; speedup vs baseline: 1.2953x; 1.2321x over previous
//
#include <hip/hip_runtime.h>

// EfficientAttention (linear attention / Performer-style), MI355X gfx950.
// B=4, S=8192, H=512, NH=8, HD=64, FD=32. All inputs fp32; output fp32.
//
// R5: K-loop reverted to the R2-proven 2-phase __syncthreads structure (the
// R3/R4 counted-vmcnt raw-barrier loop raced on graph replays). Kept from R3:
// LDS-transpose K/V epilogue (coalesced 16B stores), fused gemm_out (K=256),
// mprep/qn output-projection fusion. All LDS consumers sit behind
// __syncthreads() (which drains vmcnt(0)+lgkmcnt(0)) or own-wave lgkmcnt(0);
// no counted vmcnt anywhere.
//
//  K0a cvt_x   : x fp32 -> xb bf16
//  K0b prep_w  : WcatT[n][k] bf16 (n<256:(Wq@rm)^T, n<512:(Wk@rm)^T, else Wv^T)
//  K1  gemm_qkv: xb @ WcatT^T; elu+1 on feature cols; QF token-major,
//                KFT/VT transposed (bh,d|f,s) via per-wave LDS transpose.
//  K2  kv_part : per (b,h): kv[d][f] = sum_s k'[s][d] v[s][f]; ksum folded.
//  K2b kv_red  : partials -> kvr[bh][2080] (2048 kv + 32 ksum) fp32
//  K2c mprep   : MT[b][n][k=h*32+d] = sum_f kv[b,h,d,f]*Wout[h*64+f][n] (bf16)
//  K3  qn_kern : qn[tok][h*32+d] = q' / (q'.ksum_h + 1e-6)               (bf16)
//  K4  gemm_out: out[b] = qn[b] @ M[b]^T + b_out  (K=256, B-panel LDS-resident,
//                A-frags direct from global)

#define DEVFN static __device__ __forceinline__

typedef short short8 __attribute__((ext_vector_type(8)));
typedef __bf16 bf16x8 __attribute__((ext_vector_type(8)));
typedef float f32x4 __attribute__((ext_vector_type(4)));

DEVFN unsigned short f2bf(float x) {
  unsigned u = __float_as_uint(x);
  u += 0x7FFFu + ((u >> 16) & 1u);   // RNE
  return (unsigned short)(u >> 16);
}
DEVFN float bf2f(unsigned short s) { return __uint_as_float(((unsigned)s) << 16); }

DEVFN f32x4 mfma16(short8 a, short8 b, f32x4 c) {
  return __builtin_amdgcn_mfma_f32_16x16x32_bf16(
      __builtin_bit_cast(bf16x8, a), __builtin_bit_cast(bf16x8, b), c, 0, 0, 0);
}

DEVFN void gload16(const void* g, void* l) {
  __builtin_amdgcn_global_load_lds((__attribute__((address_space(1))) unsigned*)g,
                                   (__attribute__((address_space(3))) unsigned*)l,
                                   16, 0, 0);
}

// ---------------- K0a: x fp32 -> bf16 ----------------
__global__ __launch_bounds__(256) void cvt_x(const float* __restrict__ x,
                                             unsigned short* __restrict__ xb) {
  size_t i = ((size_t)blockIdx.x * 256 + threadIdx.x) * 8;
  f32x4 a = *(const f32x4*)(x + i);
  f32x4 b = *(const f32x4*)(x + i + 4);
  short8 o;
  o[0] = (short)f2bf(a[0]); o[1] = (short)f2bf(a[1]);
  o[2] = (short)f2bf(a[2]); o[3] = (short)f2bf(a[3]);
  o[4] = (short)f2bf(b[0]); o[5] = (short)f2bf(b[1]);
  o[6] = (short)f2bf(b[2]); o[7] = (short)f2bf(b[3]);
  *(short8*)(xb + i) = o;
}

// ---------------- K0b: weight prep ----------------
__global__ __launch_bounds__(64) void prep_w(const float* __restrict__ Wqkv,
                                             const float* __restrict__ rm,
                                             unsigned short* __restrict__ WcatT) {
  const int n = blockIdx.x, t = threadIdx.x;
  if (n < 512) {
    const int isK = (n >= 256) ? 1 : 0;
    const int c = n & 255, h = c >> 5, d = c & 31;
    const int colbase = isK * 512 + h * 64;
    for (int k = t; k < 512; k += 64) {
      float s = 0.f;
      const float* wrow = Wqkv + (size_t)k * 1536 + colbase;
      #pragma unroll 8
      for (int e = 0; e < 64; ++e) s += wrow[e] * rm[e * 32 + d];
      WcatT[(size_t)n * 512 + k] = f2bf(s);
    }
  } else {
    const int c = n - 512;
    for (int k = t; k < 512; k += 64)
      WcatT[(size_t)n * 512 + k] = f2bf(Wqkv[(size_t)k * 1536 + 1024 + c]);
  }
}

// ---------------- K1: qkv GEMM, K=512, 2-buf __syncthreads pipeline --------
__global__ __launch_bounds__(256) void gemm_qkv(
    const unsigned short* __restrict__ A,
    const unsigned short* __restrict__ BT,
    unsigned short* __restrict__ OQ,
    unsigned short* __restrict__ OK,
    unsigned short* __restrict__ OV) {
  // K-loop: A bufs [0,8192), B bufs [8192,16384) shorts (32 KB).
  // Epilogue transpose (after __syncthreads): 4 waves x 4352 shorts = 17408.
  __shared__ __attribute__((aligned(16))) unsigned short lds[18432];  // 36 KB
  const int t = threadIdx.x;
  const int lane = t & 63, w = t >> 6;
  const int wr = w >> 1, wc = w & 1;
  const int col = lane & 15, kg = lane >> 4;

  // XCD-chunked swizzle (2048 wgs, %8==0)
  const int nx = gridDim.x;
  int wg = blockIdx.y * nx + blockIdx.x;
  const int cpx = (nx * (int)gridDim.y) >> 3;
  wg = (wg & 7) * cpx + (wg >> 3);
  const int bx = wg % nx, by = wg / nx;

  const long m0 = (long)by * 128;
  const long n0 = (long)bx * 128;

  const unsigned short* ga = A + (m0 + (t >> 2)) * 512 + (t & 3) * 8;
  const unsigned short* gb = BT + (n0 + (t >> 2)) * 512 + (t & 3) * 8;

  f32x4 acc[4][4] = {};

#define STAGE(buf, kt)                                    \
  {                                                       \
    const int ko_ = (kt) * 32;                            \
    unsigned short* la_ = lds + (buf) * 4096 + w * 512;   \
    unsigned short* lb_ = lds + 8192 + (buf) * 4096 + w * 512; \
    gload16(ga + ko_, la_);                               \
    gload16(ga + 32768 + ko_, la_ + 2048);                \
    gload16(gb + ko_, lb_);                               \
    gload16(gb + 32768 + ko_, lb_ + 2048);                \
  }
  STAGE(0, 0);
  __syncthreads();                 // drains vmcnt(0): tile 0 resident
  int buf = 0;
  for (int kt = 0; kt < 16; ++kt) {
    if (kt + 1 < 16) STAGE(buf ^ 1, kt + 1);  // issue next tile early
    const unsigned short* As_ = lds + buf * 4096;
    const unsigned short* Bs_ = lds + 8192 + buf * 4096;
    short8 af[4], bfr[4];
    #pragma unroll
    for (int mi = 0; mi < 4; ++mi)
      af[mi] = *(const short8*)&As_[(wr * 64 + mi * 16 + col) * 32 + kg * 8];
    #pragma unroll
    for (int ni = 0; ni < 4; ++ni)
      bfr[ni] = *(const short8*)&Bs_[(wc * 64 + ni * 16 + col) * 32 + kg * 8];
    #pragma unroll
    for (int mi = 0; mi < 4; ++mi)
      #pragma unroll
      for (int ni = 0; ni < 4; ++ni)
        acc[mi][ni] = mfma16(af[mi], bfr[ni], acc[mi][ni]);
    __syncthreads();               // drains next-tile DMA; frees buf for reuse
    buf ^= 1;
  }
#undef STAGE

  const int rowb = (int)m0 + wr * 64;
  const int colb = (int)n0 + wc * 64;
  const int b_ = rowb >> 13, srow = rowb & 8191;

  if (colb < 256) {
    // Q quadrant: token-major direct stores, elu+1
    #pragma unroll
    for (int ni = 0; ni < 4; ++ni) {
      const int c = colb + ni * 16 + col;
      #pragma unroll
      for (int mi = 0; mi < 4; ++mi) {
        #pragma unroll
        for (int r = 0; r < 4; ++r) {
          const int row = rowb + mi * 16 + kg * 4 + r;
          float v = acc[mi][ni][r];
          v = v > 0.f ? v + 1.f : __expf(v);
          OQ[(size_t)row * 256 + c] = f2bf(v);
        }
      }
    }
  } else {
    // K/V quadrant: per-wave 64x64 LDS transpose, then coalesced 16B stores.
    // (K-loop fully done for ALL waves: last __syncthreads in loop.)
    const bool isK = (colb < 512);
    unsigned short* q_ = lds + w * 4352;   // 64 x 64, row stride 68 elements
    #pragma unroll
    for (int ni = 0; ni < 4; ++ni) {
      const int p = ni * 16 + col;
      #pragma unroll
      for (int mi = 0; mi < 4; ++mi) {
        #pragma unroll
        for (int r = 0; r < 4; ++r) {
          const int q = mi * 16 + kg * 4 + r;
          float v = acc[mi][ni][r];
          if (isK) v = v > 0.f ? v + 1.f : __expf(v);
          q_[q * 68 + p] = f2bf(v);
        }
      }
    }
    asm volatile("s_waitcnt lgkmcnt(0)" ::: "memory");  // own-wave writes done
    __builtin_amdgcn_sched_barrier(0);
    const int pg = lane >> 3, jj = lane & 7;
    #pragma unroll
    for (int it = 0; it < 8; ++it) {
      const int p = pg + it * 8;          // column of quadrant
      const int c = colb + p;
      size_t rowf;
      if (isK) rowf = (size_t)(b_ * 8 + ((c - 256) >> 5)) * 32 + ((c - 256) & 31);
      else     rowf = (size_t)(b_ * 8 + ((c - 512) >> 6)) * 64 + ((c - 512) & 63);
      unsigned short* dst = (isK ? OK : OV) + rowf * 8192 + srow + jj * 8;
      short8 o;
      #pragma unroll
      for (int i = 0; i < 8; ++i)
        o[i] = (short)q_[(jj * 8 + i) * 68 + p];
      *(short8*)dst = o;
    }
  }
}

// ---------------- K2: kv partials per (b,h), split over S ----------------
__global__ __launch_bounds__(64) void kv_partial(const unsigned short* __restrict__ KFT,
                                                 const unsigned short* __restrict__ VT,
                                                 float* __restrict__ part) {
  const int bh = blockIdx.x, chunk = blockIdx.y;
  const int l = threadIdx.x;
  const int col = l & 15, kg = l >> 4;
  const unsigned short* Ab = KFT + (size_t)bh * 32 * 8192;
  const unsigned short* Bb = VT + (size_t)bh * 64 * 8192;
  const int s0 = chunk * 256;
  f32x4 acc[2][4] = {};
  float ksp[2] = {0.f, 0.f};
  #pragma unroll 2
  for (int st = 0; st < 8; ++st) {
    const int s = s0 + st * 32 + kg * 8;
    short8 a[2], b[4];
    #pragma unroll
    for (int mi = 0; mi < 2; ++mi)
      a[mi] = *(const short8*)&Ab[(size_t)(mi * 16 + col) * 8192 + s];
    #pragma unroll
    for (int ni = 0; ni < 4; ++ni)
      b[ni] = *(const short8*)&Bb[(size_t)(ni * 16 + col) * 8192 + s];
    #pragma unroll
    for (int mi = 0; mi < 2; ++mi) {
      #pragma unroll
      for (int j = 0; j < 8; ++j) ksp[mi] += bf2f((unsigned short)a[mi][j]);
      #pragma unroll
      for (int ni = 0; ni < 4; ++ni)
        acc[mi][ni] = mfma16(a[mi], b[ni], acc[mi][ni]);
    }
  }
  #pragma unroll
  for (int mi = 0; mi < 2; ++mi) {
    float v = ksp[mi];
    v += __shfl_xor(v, 16);
    v += __shfl_xor(v, 32);
    ksp[mi] = v;
  }
  float* p = part + ((size_t)bh * 32 + chunk) * 2080;
  #pragma unroll
  for (int mi = 0; mi < 2; ++mi)
    #pragma unroll
    for (int ni = 0; ni < 4; ++ni)
      #pragma unroll
      for (int r = 0; r < 4; ++r) {
        const int d = mi * 16 + kg * 4 + r, f = ni * 16 + col;
        p[d * 64 + f] = acc[mi][ni][r];
      }
  if (kg == 0) {
    p[2048 + col] = ksp[0];
    p[2048 + 16 + col] = ksp[1];
  }
}

// ---------------- K2b: reduce partials ----------------
__global__ __launch_bounds__(256) void kv_reduce(const float* __restrict__ part,
                                                 float* __restrict__ kvr) {
  const int bh = blockIdx.x, t = threadIdx.x;
  for (int idx = t; idx < 2080; idx += 256) {
    float s = 0.f;
    for (int c = 0; c < 32; ++c) s += part[((size_t)bh * 32 + c) * 2080 + idx];
    kvr[(size_t)bh * 2080 + idx] = s;
  }
}

// ---------------- K2c: MT[b][n][k=h*32+d] ----------------
__global__ __launch_bounds__(256) void mprep(const float* __restrict__ kvr,
                                             const float* __restrict__ Wout,
                                             unsigned short* __restrict__ MT) {
  const int bx = blockIdx.x;            // 0..2047
  const int b = bx >> 9, n = bx & 511;
  const int k = threadIdx.x;            // 0..255
  const int h = k >> 5, d = k & 31;
  const float* kvp = kvr + (size_t)(b * 8 + h) * 2080 + d * 64;
  const float* wp = Wout + (size_t)h * 64 * 512 + n;
  float s = 0.f;
  #pragma unroll 8
  for (int f = 0; f < 64; ++f) s += kvp[f] * wp[(size_t)f * 512];
  MT[((size_t)b * 512 + n) * 256 + k] = f2bf(s);
}

// ---------------- K3: qn = q' / (q'.ksum + 1e-6) ----------------
__global__ __launch_bounds__(256) void qn_kernel(const unsigned short* __restrict__ QF,
                                                 const float* __restrict__ kvr,
                                                 unsigned short* __restrict__ QN) {
  __shared__ float ks[256];
  const int t = threadIdx.x;
  const size_t tid = (size_t)blockIdx.x * 256 + t;
  const int tok0 = blockIdx.x * 32;
  const int b = tok0 >> 13;
  ks[t] = kvr[(size_t)(b * 8 + (t >> 5)) * 2080 + 2048 + (t & 31)];
  __syncthreads();
  const int tok = (int)(tid >> 3), h = (int)(tid & 7);
  const short8* q = (const short8*)(QF + (size_t)tok * 256 + h * 32);
  short8 v[4];
  #pragma unroll
  for (int i = 0; i < 4; ++i) v[i] = q[i];
  float den = 1e-6f;
  #pragma unroll
  for (int i = 0; i < 4; ++i)
    #pragma unroll
    for (int j = 0; j < 8; ++j)
      den += bf2f((unsigned short)v[i][j]) * ks[h * 32 + i * 8 + j];
  const float inv = 1.f / den;
  short8* o = (short8*)(QN + (size_t)tok * 256 + h * 32);
  #pragma unroll
  for (int i = 0; i < 4; ++i) {
    short8 ov;
    #pragma unroll
    for (int j = 0; j < 8; ++j)
      ov[j] = (short)f2bf(bf2f((unsigned short)v[i][j]) * inv);
    o[i] = ov;
  }
}

// ---------------- K4: out = qn @ M^T + bias (K=256) ----------------
__global__ __launch_bounds__(256) void gemm_out(
    const unsigned short* __restrict__ QN,   // 32768 x 256
    const unsigned short* __restrict__ MT,   // [4][512][256]
    const float* __restrict__ bias,
    float* __restrict__ OC) {
  __shared__ __attribute__((aligned(16))) unsigned short Bls[32768];  // 64 KB
  const int t = threadIdx.x;
  const int lane = t & 63, w = t >> 6;
  const int wr = w >> 1, wc = w & 1;
  const int col = lane & 15, kg = lane >> 4;

  const int nx = gridDim.x;
  int wg = blockIdx.y * nx + blockIdx.x;
  const int cpx = (nx * (int)gridDim.y) >> 3;
  wg = (wg & 7) * cpx + (wg >> 3);
  const int bx = wg % nx, by = wg / nx;
  const long m0 = (long)by * 128;
  const long n0 = (long)bx * 128;
  const long b = m0 >> 13;
  const unsigned short* MTb = MT + b * 512 * 256;

  #pragma unroll
  for (int i = 0; i < 16; ++i) {   // 16 x 4KB = 64KB staged
    const int u = i * 256 + t;
    const int slab = u >> 9, row = (u >> 2) & 127, ch = u & 3;
    gload16(MTb + ((size_t)(n0 + row)) * 256 + slab * 32 + ch * 8,
            Bls + ((size_t)i * 256 + w * 64) * 8);
  }
  __syncthreads();   // drains vmcnt(0): whole B-panel resident

  f32x4 acc[4][4] = {};
  #pragma unroll 2
  for (int kt = 0; kt < 8; ++kt) {
    short8 af[4], bfr[4];
    #pragma unroll
    for (int mi = 0; mi < 4; ++mi)
      af[mi] = *(const short8*)&QN[(m0 + wr * 64 + mi * 16 + col) * 256 +
                                   kt * 32 + kg * 8];
    #pragma unroll
    for (int ni = 0; ni < 4; ++ni)
      bfr[ni] = *(const short8*)&Bls[kt * 4096 +
                                     (wc * 64 + ni * 16 + col) * 32 + kg * 8];
    #pragma unroll
    for (int mi = 0; mi < 4; ++mi)
      #pragma unroll
      for (int ni = 0; ni < 4; ++ni)
        acc[mi][ni] = mfma16(af[mi], bfr[ni], acc[mi][ni]);
  }

  const int rowb = (int)m0 + wr * 64;
  const int colb = (int)n0 + wc * 64;
  #pragma unroll
  for (int ni = 0; ni < 4; ++ni) {
    const int c = colb + ni * 16 + col;
    const float bb = bias[c];
    #pragma unroll
    for (int mi = 0; mi < 4; ++mi) {
      #pragma unroll
      for (int r = 0; r < 4; ++r) {
        const int row = rowb + mi * 16 + kg * 4 + r;
        OC[(size_t)row * 512 + c] = acc[mi][ni][r] + bb;
      }
    }
  }
}

extern "C" void kernel_launch(void* const* d_in, const int* in_sizes, int n_in,
                              void* d_out, int out_size, void* d_ws, size_t ws_size,
                              hipStream_t stream) {
  const float* x    = (const float*)d_in[0];
  const float* Wqkv = (const float*)d_in[1];
  const float* rm   = (const float*)d_in[2];
  const float* Wout = (const float*)d_in[3];
  const float* bout = (const float*)d_in[4];
  float* out = (float*)d_out;

  char* ws = (char*)d_ws;
  unsigned short* xb    = (unsigned short*)(ws);              // 33,554,432 B
  unsigned short* WcatT = (unsigned short*)(ws + 33554432);   //  1,048,576
  unsigned short* QF    = (unsigned short*)(ws + 35127296);   // 16,777,216
  unsigned short* KFT   = (unsigned short*)(ws + 51904512);   // 16,777,216
  unsigned short* VT    = (unsigned short*)(ws + 68681728);   // 33,554,432
  float* part           = (float*)(ws + 102236160);           //  8,519,680
  float* kvr            = (float*)(ws + 110755840);           //    266,240
  unsigned short* QN = xb;                                    // alias (xb dead)
  unsigned short* MT = (unsigned short*)(ws + 16777216);      // alias (xb dead)

  if (ws_size < 111022080u) return;

  cvt_x<<<dim3(8192), dim3(256), 0, stream>>>(x, xb);
  prep_w<<<dim3(1024), dim3(64), 0, stream>>>(Wqkv, rm, WcatT);
  gemm_qkv<<<dim3(8, 256), dim3(256), 0, stream>>>(xb, WcatT, QF, KFT, VT);
  kv_partial<<<dim3(32, 32), dim3(64), 0, stream>>>(KFT, VT, part);
  kv_reduce<<<dim3(32), dim3(256), 0, stream>>>(part, kvr);
  mprep<<<dim3(2048), dim3(256), 0, stream>>>(kvr, Wout, MT);
  qn_kernel<<<dim3(1024), dim3(256), 0, stream>>>(QF, kvr, QN);
  gemm_out<<<dim3(4, 256), dim3(256), 0, stream>>>(QN, MT, bout, out);
}